// Round 12
// baseline (522.651 us; speedup 1.0000x reference)
//
#include <hip/hip_runtime.h>

// Problem constants
#define M_TOKENS 65536      // 8 * 8192
#define HID      256
#define KCODES   512

#define IND_OFF  (M_TOKENS * HID)          // 16777216
#define LOSS_OFF (IND_OFF + M_TOKENS)      // 16842752

// Flag threshold: tokens whose fine top-2 gap <= TAU get exact in-block
// re-resolution over the top-3 candidates with the emulated reference-f32
// quantization pipeline. Quantization can only flip candidates within
// 2*1.5*grid ~ 9.2e-5 < TAU of the min.
#define TAU      1.5e-4f

// ws layout:
//   [0:8) double loss | [8:12) int cnt (fallback) | [12:16) int done
//   [16:2064) c2[512]
//   [4096 : +256K) B_hi fragments | [266240 : +256K) B_lo | [528384 : +32K) list
#define WS_C2_OFF        16
#define WS_BHI_OFF       4096
#define WS_BLO_OFF       (4096 + 262144)
#define WS_LIST_OFF_FAST (4096 + 524288)
#define WS_LIST_OFF_SLOW 4096
#define WS_MIN_FAST      (WS_LIST_OFF_FAST + 8192 * 4)

typedef __attribute__((ext_vector_type(8))) short  short8;   // 8 bf16
typedef __attribute__((ext_vector_type(4))) float  f32x4;

__device__ inline unsigned short f2bf(float f) {             // RNE f32->bf16
    unsigned u = __float_as_uint(f);
    u += 0x7FFF + ((u >> 16) & 1);
    return (unsigned short)(u >> 16);
}
__device__ inline float bf2f(unsigned short h) {
    return __uint_as_float(((unsigned)h) << 16);
}

// lexicographic top-3 insert: (score asc, index asc on ties)
__device__ inline void ins3(float s, int i,
                            float& b1, int& i1, float& b2, int& i2,
                            float& b3, int& i3) {
    if (s < b1 || (s == b1 && i < i1)) {
        b3 = b2; i3 = i2; b2 = b1; i2 = i1; b1 = s; i1 = i;
    } else if (s < b2 || (s == b2 && i < i2)) {
        b3 = b2; i3 = i2; b2 = s; i2 = i;
    } else if (s < b3 || (s == b3 && i < i3)) {
        b3 = s; i3 = i;
    }
}

// ---------------------------------------------------------------------------
// prep: blocks 0..63 swizzle codebook into MFMA B-fragment order (bf16 hi/lo);
//       blocks 64..65 compute c2[k] (f64) and zero the accumulators.
// ---------------------------------------------------------------------------
__global__ __launch_bounds__(256) void vq_prep(
    const float* __restrict__ cb,
    unsigned short* __restrict__ Bhi, unsigned short* __restrict__ Blo,
    float* __restrict__ c2, double* __restrict__ acc,
    int* __restrict__ cnt, int* __restrict__ done) {
    int b = blockIdx.x;
    if (b < 64) {
        int g = b * 256 + threadIdx.x;   // 0..16383 = frag*64 + lane
        int frag = g >> 6, lane = g & 63;
        int nb = frag >> 3, kb = frag & 7;
        int code = nb * 16 + (lane & 15);
        int kk = kb * 32 + (lane >> 4) * 8;
        const float4* s4 = reinterpret_cast<const float4*>(cb + code * HID + kk);
        float4 v0 = s4[0], v1 = s4[1];
        float f[8] = {v0.x, v0.y, v0.z, v0.w, v1.x, v1.y, v1.z, v1.w};
        short8 vh, vl;
        #pragma unroll
        for (int j = 0; j < 8; ++j) {
            unsigned short h = f2bf(f[j]);
            vh[j] = (short)h;
            vl[j] = (short)f2bf(f[j] - bf2f(h));
        }
        *reinterpret_cast<short8*>(Bhi + (size_t)g * 8) = vh;
        *reinterpret_cast<short8*>(Blo + (size_t)g * 8) = vl;
    } else {
        if (b == 64 && threadIdx.x == 0) { *acc = 0.0; *cnt = 0; *done = 0; }
        int k = (b - 64) * 256 + threadIdx.x;   // 0..511
        const float* row = cb + k * HID;
        double s = 0.0;
        for (int i = 0; i < HID; ++i) {
            double v = (double)row[i];
            s = fma(v, v, s);
        }
        c2[k] = (float)s;
    }
}

// ---------------------------------------------------------------------------
// main MFMA kernel (round-10 geometry, the measured best: 110us):
// 256 threads = 4 waves; wave owns 32 tokens (2 M-frags); grid 512 blocks
// (2 blocks/CU). BK=32 codes/phase, 16 phases, double-buffered 32KB LDS via
// global_load_lds; setprio around MFMA clusters. Loss algebraic.
// NEW: top-3 tracking; flagged tokens refined IN-BLOCK (f64 candidate dots,
// emulated reference-f32 quantization pipeline); last block finalizes loss.
// Fast path = 2 kernel launches total.
// ---------------------------------------------------------------------------
__global__ __launch_bounds__(256, 2) void vq_main_mfma(
    const float* __restrict__ z, const float* __restrict__ cb,
    const float* __restrict__ c2g,
    const unsigned short* __restrict__ Bhi,
    const unsigned short* __restrict__ Blo,
    float* __restrict__ out, double* __restrict__ loss_acc,
    int* __restrict__ done) {

    __shared__ short8 ldsB[2][32][64];   // 2 bufs x 32KB = 64 KB
    __shared__ float  lds_c2[KCODES];    // 2 KB

    const int tid  = threadIdx.x;
    const int wid  = tid >> 6;
    const int lane = tid & 63;
    const int q    = lane >> 4;
    const int tokW = blockIdx.x * 128 + wid * 32;   // wave's first token

    const float4* z4  = reinterpret_cast<const float4*>(z);
    const float4* cb4 = reinterpret_cast<const float4*>(cb);

    // stage c2 into LDS
    lds_c2[tid]       = c2g[tid];
    lds_c2[tid + 256] = c2g[tid + 256];

    // stage one 32-code phase (32 frag-slots of 1KB): wave wid stages slots
    // wid*8 .. wid*8+7.  Slot s: g=s>>4 (16-code group), t=s&15 (0..7 hi,
    // 8..15 lo), kb=t&7.  Source frag index nb = 2*phase+g.
#define STAGE(kv, bufv) do {                                                   \
        _Pragma("unroll")                                                      \
        for (int j = 0; j < 8; ++j) {                                          \
            int s_  = (wid << 3) | j;                                          \
            int g_  = s_ >> 4;                                                 \
            int t_  = s_ & 15;                                                 \
            int kb_ = t_ & 7;                                                  \
            const unsigned short* src_ =                                       \
                ((t_ < 8) ? Bhi : Blo) +                                       \
                (((size_t)((2 * (kv) + g_) * 8 + kb_) * 64 + lane) << 3);      \
            __builtin_amdgcn_global_load_lds(                                  \
                (const __attribute__((address_space(1))) void*)src_,           \
                (__attribute__((address_space(3))) void*)&ldsB[bufv][s_][0],   \
                16, 0, 0);                                                     \
        }                                                                      \
    } while (0)

    // issue phase-0 stage FIRST so it streams in under the A-load/convert
    STAGE(0, 0);

    // ---- load wave's 32 z rows as A fragments (bf16 hi/lo) + z2 ----
    short8 ah[2][8], al[2][8];
    float sq[2];
    #pragma unroll
    for (int mf = 0; mf < 2; ++mf) {
        int token = tokW + mf * 16 + (lane & 15);
        const float4* zr = z4 + (size_t)token * 64 + q * 2;
        float s = 0.f;
        #pragma unroll
        for (int kb = 0; kb < 8; ++kb) {
            float4 v0 = zr[kb * 8];
            float4 v1 = zr[kb * 8 + 1];
            float f[8] = {v0.x, v0.y, v0.z, v0.w, v1.x, v1.y, v1.z, v1.w};
            short8 vh, vl;
            #pragma unroll
            for (int j = 0; j < 8; ++j) {
                unsigned short h = f2bf(f[j]);
                vh[j] = (short)h;
                vl[j] = (short)f2bf(f[j] - bf2f(h));
                s = fmaf(f[j], f[j], s);
            }
            ah[mf][kb] = vh;
            al[mf][kb] = vl;
        }
        s += __shfl_xor(s, 16, 64);
        s += __shfl_xor(s, 32, 64);
        sq[mf] = s;
    }

    // per-lane running top-3 for 2 mfrags x 4 rows
    float b1[2][4], b2[2][4], b3[2][4];
    int   i1[2][4], i2[2][4], i3[2][4];
    #pragma unroll
    for (int mf = 0; mf < 2; ++mf)
        #pragma unroll
        for (int r = 0; r < 4; ++r) {
            b1[mf][r] = 3.4e38f; b2[mf][r] = 3.4e38f; b3[mf][r] = 3.4e38f;
            i1[mf][r] = 0; i2[mf][r] = 0; i3[mf][r] = 0;
        }

    // ---- main loop over 16 phases of 32 codes; dbuf, 1 barrier/phase ----
    #pragma unroll 2
    for (int k = 0; k < 16; ++k) {
        int buf = k & 1;
        __syncthreads();                    // phase-k data landed; buf^1 free
        if (k < 15) STAGE(k + 1, buf ^ 1);  // async prefetch under compute

        #pragma unroll
        for (int g = 0; g < 2; ++g) {
            f32x4 a0 = {0.f, 0.f, 0.f, 0.f};
            f32x4 a1 = {0.f, 0.f, 0.f, 0.f};
            __builtin_amdgcn_s_setprio(1);
            #pragma unroll
            for (int kb = 0; kb < 8; ++kb) {
                short8 vbh = ldsB[buf][g * 16 + kb][lane];
                short8 vbl = ldsB[buf][g * 16 + 8 + kb][lane];
                a0 = __builtin_amdgcn_mfma_f32_16x16x32_bf16(ah[0][kb], vbh, a0, 0, 0, 0);
                a1 = __builtin_amdgcn_mfma_f32_16x16x32_bf16(ah[1][kb], vbh, a1, 0, 0, 0);
                a0 = __builtin_amdgcn_mfma_f32_16x16x32_bf16(al[0][kb], vbh, a0, 0, 0, 0);
                a1 = __builtin_amdgcn_mfma_f32_16x16x32_bf16(al[1][kb], vbh, a1, 0, 0, 0);
                a0 = __builtin_amdgcn_mfma_f32_16x16x32_bf16(ah[0][kb], vbl, a0, 0, 0, 0);
                a1 = __builtin_amdgcn_mfma_f32_16x16x32_bf16(ah[1][kb], vbl, a1, 0, 0, 0);
            }
            __builtin_amdgcn_s_setprio(0);
            int code = (2 * k + g) * 16 + (lane & 15);
            float c2v = lds_c2[code];
            #pragma unroll
            for (int r = 0; r < 4; ++r) {
                float s0 = fmaf(-2.f, a0[r], c2v);   // c2 - 2*cross
                ins3(s0, code, b1[0][r], i1[0][r], b2[0][r], i2[0][r], b3[0][r], i3[0][r]);
                float s1 = fmaf(-2.f, a1[r], c2v);
                ins3(s1, code, b1[1][r], i1[1][r], b2[1][r], i2[1][r], b3[1][r], i3[1][r]);
            }
        }
    }
#undef STAGE

    // scratch region in dead ldsB: flags [128][4] ints, counter, f64 partials
    char*   sbase = (char*)(&ldsB[0][0][0]);
    int*    flg   = (int*)sbase;              // [128][4] = 2048 B
    int*    fcnt  = (int*)(sbase + 2048);
    double* wred  = (double*)(sbase + 2056);  // [4 waves][4 vals]
    int*    bslot = (int*)(sbase + 2184);

    __syncthreads();                          // all waves done with ldsB
    if (tid == 0) *fcnt = 0;

    // ---- merge top-3 across the 16 lanes of each row group ----
    #pragma unroll
    for (int st = 1; st <= 8; st <<= 1) {
        #pragma unroll
        for (int mf = 0; mf < 2; ++mf)
            #pragma unroll
            for (int r = 0; r < 4; ++r) {
                float o1 = __shfl_xor(b1[mf][r], st, 64);
                int   j1 = __shfl_xor(i1[mf][r], st, 64);
                float o2 = __shfl_xor(b2[mf][r], st, 64);
                int   j2 = __shfl_xor(i2[mf][r], st, 64);
                float o3 = __shfl_xor(b3[mf][r], st, 64);
                int   j3 = __shfl_xor(i3[mf][r], st, 64);
                ins3(o1, j1, b1[mf][r], i1[mf][r], b2[mf][r], i2[mf][r], b3[mf][r], i3[mf][r]);
                ins3(o2, j2, b1[mf][r], i1[mf][r], b2[mf][r], i2[mf][r], b3[mf][r], i3[mf][r]);
                ins3(o3, j3, b1[mf][r], i1[mf][r], b2[mf][r], i2[mf][r], b3[mf][r], i3[mf][r]);
            }
    }
    __syncthreads();                          // fcnt=0 visible to all

    // ---- indices + flag push (token + top-3 candidates) ----
    if ((lane & 15) == 0) {
        #pragma unroll
        for (int mf = 0; mf < 2; ++mf) {
            float4 iv;
            #pragma unroll
            for (int r = 0; r < 4; ++r) {
                ((float*)&iv)[r] = (float)i1[mf][r];
                if (b2[mf][r] - b1[mf][r] <= TAU) {
                    int pos = atomicAdd(fcnt, 1);
                    if (pos < 128) {
                        flg[pos * 4 + 0] = tokW + mf * 16 + q * 4 + r;
                        flg[pos * 4 + 1] = i1[mf][r];
                        flg[pos * 4 + 2] = i2[mf][r];
                        flg[pos * 4 + 3] = i3[mf][r];
                    }
                }
            }
            *reinterpret_cast<float4*>(out + IND_OFF + tokW + mf * 16 + q * 4) = iv;
        }
    }

    // ---- loss: ||zq-z||^2 = z2 + (c2_best - 2 cross_best) = z2 + b1 ----
    double lsum = 0.0;
    #pragma unroll
    for (int mf = 0; mf < 2; ++mf)
        #pragma unroll
        for (int r = 0; r < 4; ++r) {
            float z2r = __shfl(sq[mf], (lane & 48) | (q * 4 + r), 64);
            if ((lane & 15) == 0) lsum += (double)z2r + (double)b1[mf][r];
        }
    lsum += __shfl_xor(lsum, 16, 64);
    lsum += __shfl_xor(lsum, 32, 64);
    if (lane == 0) atomicAdd(loss_acc, lsum);

    // ---- gather z_q rows from codebook, write out ----
    float4* out4 = reinterpret_cast<float4*>(out);
    #pragma unroll
    for (int tt = 0; tt < 32; ++tt) {
        int code = __shfl(i1[tt >> 4][tt & 3], ((tt >> 2) & 3) * 16, 64);
        float4 cv = cb4[(size_t)code * 64 + lane];
        out4[(size_t)(tokW + tt) * 64 + lane] = cv;
    }

    // ---- in-block exact refine of flagged tokens ----
    __syncthreads();                          // flags/fcnt final
    int n = *fcnt; if (n > 128) n = 128;
    for (int f = 0; f < n; ++f) {
        int tok  = flg[f * 4 + 0];
        int c0   = flg[f * 4 + 1];
        int c1   = flg[f * 4 + 2];
        int c2i  = flg[f * 4 + 3];
        float zi = z[(size_t)tok * HID + tid];
        double p0 = (double)zi * (double)zi;
        double p1 = (double)zi * (double)cb[(size_t)c0 * HID + tid];
        double p2 = (double)zi * (double)cb[(size_t)c1 * HID + tid];
        double p3 = (double)zi * (double)cb[(size_t)c2i * HID + tid];
        #pragma unroll
        for (int off = 1; off < 64; off <<= 1) {
            p0 += __shfl_xor(p0, off, 64);
            p1 += __shfl_xor(p1, off, 64);
            p2 += __shfl_xor(p2, off, 64);
            p3 += __shfl_xor(p3, off, 64);
        }
        if (lane == 0) {
            wred[wid * 4 + 0] = p0; wred[wid * 4 + 1] = p1;
            wred[wid * 4 + 2] = p2; wred[wid * 4 + 3] = p3;
        }
        __syncthreads();
        if (tid == 0) {
            double dz2 = wred[0] + wred[4] + wred[8] + wred[12];
            float z2f = (float)dz2;
            int cand[3] = {c0, c1, c2i};
            float bD = 0.f; int bK = -1;
            #pragma unroll
            for (int j = 0; j < 3; ++j) {
                double dc = wred[1 + j] + wred[5 + j] + wred[9 + j] + wred[13 + j];
                float cross32 = (float)dc;                     // fl32(cross)
                float u = 2.0f * cross32;                      // exact
                float tq = (float)((double)z2f - (double)u);   // fl32(z2-u)
                float D = (float)((double)tq + (double)lds_c2[cand[j]]);
                int kk = cand[j];
                if (bK < 0 || D < bD || (D == bD && kk < bK)) { bD = D; bK = kk; }
            }
            *bslot = bK;
            out[IND_OFF + tok] = (float)bK;
        }
        __syncthreads();
        int best = *bslot;
        out[(size_t)tok * HID + tid] = cb[(size_t)best * HID + tid];
        __syncthreads();
    }

    // ---- last block finalizes loss ----
    if (tid == 0) {
        __threadfence();
        int d = atomicAdd(done, 1);
        if (d == (int)gridDim.x - 1) {
            double v = atomicAdd(loss_acc, 0.0);   // coherent read
            out[LOSS_OFF] = (float)(2.0 * v / (double)M_TOKENS / (double)HID);
        }
    }
}

// ---------------------------------------------------------------------------
// FALLBACK (small ws): round-3 f32 VALU kernel + batched refine.
// ---------------------------------------------------------------------------
#define BM   128
#define NC   128
#define KS   32
#define PAD  33

__global__ void vq_init(const float* __restrict__ cb, float* __restrict__ c2,
                        double* __restrict__ acc, int* __restrict__ cnt) {
    int k = threadIdx.x;
    if (k == 0) { *acc = 0.0; *cnt = 0; }
    const float* row = cb + k * HID;
    double s = 0.0;
    for (int i = 0; i < HID; ++i) {
        double v = (double)row[i];
        s = fma(v, v, s);
    }
    c2[k] = (float)s;
}

__global__ __launch_bounds__(256, 2) void vq_main_f32(
    const float* __restrict__ z, const float* __restrict__ cb,
    const float* __restrict__ c2g, float* __restrict__ out,
    double* __restrict__ loss_acc, int* __restrict__ cnt,
    int* __restrict__ list, int cap) {

    __shared__ float smem[(BM + NC) * PAD];
    float* zs = smem;
    float* cs = smem + BM * PAD;

    const int tid = threadIdx.x;
    const int tx = tid & 15;
    const int ty = tid >> 4;
    const int tokBase = blockIdx.x * BM;

    const float4* z4g  = reinterpret_cast<const float4*>(z);
    const float4* cb4g = reinterpret_cast<const float4*>(cb);

    float bs[8], bs2[8];
    int   bi[8];
    #pragma unroll
    for (int m = 0; m < 8; ++m) { bs[m] = 3.4e38f; bs2[m] = 3.4e38f; bi[m] = 0; }

    for (int chunk = 0; chunk < KCODES / NC; ++chunk) {
        float acc[8][8];
        #pragma unroll
        for (int m = 0; m < 8; ++m)
            #pragma unroll
            for (int n = 0; n < 8; ++n) acc[m][n] = 0.f;

        for (int ks = 0; ks < HID / KS; ++ks) {
            __syncthreads();
            #pragma unroll
            for (int i = 0; i < 4; ++i) {
                int f   = tid + i * 256;
                int row = f >> 3;
                int k4  = f & 7;
                float4 zv = z4g[(tokBase + row) * (HID / 4) + ks * (KS / 4) + k4];
                int b = row * PAD + k4 * 4;
                zs[b + 0] = zv.x; zs[b + 1] = zv.y; zs[b + 2] = zv.z; zs[b + 3] = zv.w;
                float4 cv = cb4g[(chunk * NC + row) * (HID / 4) + ks * (KS / 4) + k4];
                cs[b + 0] = cv.x; cs[b + 1] = cv.y; cs[b + 2] = cv.z; cs[b + 3] = cv.w;
            }
            __syncthreads();

            #pragma unroll 2
            for (int k = 0; k < KS; ++k) {
                float zf[8], cf[8];
                #pragma unroll
                for (int m = 0; m < 8; ++m) zf[m] = zs[(ty * 8 + m) * PAD + k];
                #pragma unroll
                for (int n = 0; n < 8; ++n) cf[n] = cs[(tx * 8 + n) * PAD + k];
                #pragma unroll
                for (int m = 0; m < 8; ++m)
                    #pragma unroll
                    for (int n = 0; n < 8; ++n)
                        acc[m][n] = fmaf(zf[m], cf[n], acc[m][n]);
            }
        }

        #pragma unroll
        for (int n = 0; n < 8; ++n) {
            int code = chunk * NC + tx * 8 + n;
            float c2v = c2g[code];
            #pragma unroll
            for (int m = 0; m < 8; ++m) {
                float s = fmaf(-2.f, acc[m][n], c2v);
                if (s < bs[m]) { bs2[m] = bs[m]; bs[m] = s; bi[m] = code; }
                else if (s < bs2[m]) bs2[m] = s;
            }
        }
    }

    __syncthreads();
    float* rs   = smem;
    int*   ri   = reinterpret_cast<int*>(smem + BM * 16);
    float* rs2  = smem + BM * 32;
    int*   inds = reinterpret_cast<int*>(smem + BM * 48);
    float* wred = smem + BM * 48 + BM;

    #pragma unroll
    for (int m = 0; m < 8; ++m) {
        int tok = ty * 8 + m;
        rs [tok * 16 + tx] = bs[m];
        ri [tok * 16 + tx] = bi[m];
        rs2[tok * 16 + tx] = bs2[m];
    }
    __syncthreads();

    if (tid < BM) {
        float B1 = rs[tid * 16];
        int   I1 = ri[tid * 16];
        float B2 = rs2[tid * 16];
        for (int j = 1; j < 16; ++j) {
            float b1v = rs [tid * 16 + j];
            int   i1v = ri [tid * 16 + j];
            float b2v = rs2[tid * 16 + j];
            if (b1v < B1 || (b1v == B1 && i1v < I1)) {
                B2 = fminf(B1, b2v); B1 = b1v; I1 = i1v;
            } else {
                B2 = fminf(B2, b1v);
            }
        }
        inds[tid] = I1;
        out[IND_OFF + tokBase + tid] = (float)I1;
        if (B2 - B1 <= TAU) {
            int pos = atomicAdd(cnt, 1);
            if (pos < cap) list[pos] = tokBase + tid;
        }
    }
    __syncthreads();

    float loc = 0.f;
    float4* out4 = reinterpret_cast<float4*>(out);
    for (int it = 0; it < (BM * HID / 4) / 256; ++it) {
        int e4  = it * 256 + tid;
        int tok = e4 >> 6;
        int h4  = e4 & 63;
        int code = inds[tok];
        float4 cv = cb4g[code * 64 + h4];
        float4 zv = z4g[(tokBase + tok) * 64 + h4];
        out4[(tokBase + tok) * 64 + h4] = cv;
        float dx = cv.x - zv.x, dy = cv.y - zv.y;
        float dz = cv.z - zv.z, dw = cv.w - zv.w;
        loc = fmaf(dx, dx, loc);
        loc = fmaf(dy, dy, loc);
        loc = fmaf(dz, dz, loc);
        loc = fmaf(dw, dw, loc);
    }
    #pragma unroll
    for (int off = 32; off > 0; off >>= 1) loc += __shfl_xor(loc, off, 64);
    int wave = tid >> 6;
    if ((tid & 63) == 0) wred[wave] = loc;
    __syncthreads();
    if (tid == 0) {
        double t = (double)wred[0] + (double)wred[1] +
                   (double)wred[2] + (double)wred[3];
        atomicAdd(loss_acc, t);
    }
}

#define RT 8
__global__ __launch_bounds__(256) void vq_refine(
    const float* __restrict__ z, const float* __restrict__ cb,
    const float* __restrict__ c2g, const double* __restrict__ loss_acc,
    const int* __restrict__ cnt, const int* __restrict__ list,
    float* __restrict__ out, int cap) {

    if (blockIdx.x == 0 && threadIdx.x == 0)
        out[LOSS_OFF] = (float)(2.0 * (*loss_acc) / (double)(M_TOKENS * HID));

    __shared__ float  zrow[RT][HID];
    __shared__ double redd[RT][256];
    __shared__ int    redi[RT][256];

    const int tid = threadIdx.x;
    int n = *cnt; if (n > cap) n = cap;

    for (int base = blockIdx.x * RT; base < n; base += gridDim.x * RT) {
        int toks[RT];
        #pragma unroll
        for (int t = 0; t < RT; ++t) {
            int ii = base + t;
            if (ii > n - 1) ii = n - 1;
            toks[t] = list[ii];
        }
        #pragma unroll
        for (int t = 0; t < RT; ++t) {
            float v = z[(size_t)toks[t] * HID + tid];
            zrow[t][tid] = v;
            redd[t][tid] = (double)v * (double)v;
        }
        __syncthreads();
        for (int s = 128; s > 0; s >>= 1) {
            if (tid < s) {
                #pragma unroll
                for (int t = 0; t < RT; ++t) redd[t][tid] += redd[t][tid + s];
            }
            __syncthreads();
        }
        float z2f[RT];
        #pragma unroll
        for (int t = 0; t < RT; ++t) z2f[t] = (float)redd[t][0];
        __syncthreads();

        double bd[RT];
        int    bk[RT];
        #pragma unroll
        for (int t = 0; t < RT; ++t) { bd[t] = 1e300; bk[t] = 1 << 30; }

        for (int c = 0; c < 2; ++c) {
            int k = tid + c * 256;
            const float4* cr = reinterpret_cast<const float4*>(cb + (size_t)k * HID);
            double acc[RT];
            #pragma unroll
            for (int t = 0; t < RT; ++t) acc[t] = 0.0;
            for (int i = 0; i < HID / 4; ++i) {
                float4 cv = cr[i];
                #pragma unroll
                for (int t = 0; t < RT; ++t) {
                    float4 zv = *reinterpret_cast<const float4*>(&zrow[t][i * 4]);
                    acc[t] = fma((double)zv.x, (double)cv.x, acc[t]);
                    acc[t] = fma((double)zv.y, (double)cv.y, acc[t]);
                    acc[t] = fma((double)zv.z, (double)cv.z, acc[t]);
                    acc[t] = fma((double)zv.w, (double)cv.w, acc[t]);
                }
            }
            float c2v = c2g[k];
            #pragma unroll
            for (int t = 0; t < RT; ++t) {
                float cross32 = (float)acc[t];
                float u = 2.0f * cross32;
                float tq = (float)((double)z2f[t] - (double)u);
                float D = (float)((double)tq + (double)c2v);
                double Dd = (double)D;
                if (Dd < bd[t] || (Dd == bd[t] && k < bk[t])) { bd[t] = Dd; bk[t] = k; }
            }
        }
        #pragma unroll
        for (int t = 0; t < RT; ++t) { redd[t][tid] = bd[t]; redi[t][tid] = bk[t]; }
        __syncthreads();
        for (int s = 128; s > 0; s >>= 1) {
            if (tid < s) {
                #pragma unroll
                for (int t = 0; t < RT; ++t) {
                    double d2 = redd[t][tid + s]; int i2v = redi[t][tid + s];
                    if (d2 < redd[t][tid] ||
                        (d2 == redd[t][tid] && i2v < redi[t][tid])) {
                        redd[t][tid] = d2; redi[t][tid] = i2v;
                    }
                }
            }
            __syncthreads();
        }
        if (tid < RT) out[IND_OFF + toks[tid]] = (float)redi[tid][0];
        #pragma unroll
        for (int t = 0; t < RT; ++t) {
            int best = redi[t][0];
            out[(size_t)toks[t] * HID + tid] = cb[(size_t)best * HID + tid];
        }
        __syncthreads();
    }
}

extern "C" void kernel_launch(void* const* d_in, const int* in_sizes, int n_in,
                              void* d_out, int out_size, void* d_ws, size_t ws_size,
                              hipStream_t stream) {
    const float* z  = (const float*)d_in[0];
    const float* cb = (const float*)d_in[1];
    float* out = (float*)d_out;
    double* acc = (double*)d_ws;
    int*  cnt  = (int*)((char*)d_ws + 8);
    int*  done = (int*)((char*)d_ws + 12);
    float* c2  = (float*)((char*)d_ws + WS_C2_OFF);

    if (ws_size >= WS_MIN_FAST) {
        unsigned short* Bhi = (unsigned short*)((char*)d_ws + WS_BHI_OFF);
        unsigned short* Blo = (unsigned short*)((char*)d_ws + WS_BLO_OFF);
        vq_prep<<<66, 256, 0, stream>>>(cb, Bhi, Blo, c2, acc, cnt, done);
        vq_main_mfma<<<M_TOKENS / 128, 256, 0, stream>>>(
            z, cb, c2, Bhi, Blo, out, acc, done);
    } else {
        int* list = (int*)((char*)d_ws + WS_LIST_OFF_SLOW);
        int cap = 0;
        if (ws_size > WS_LIST_OFF_SLOW + 16) {
            size_t avail = (ws_size - WS_LIST_OFF_SLOW) / 4;
            cap = (avail > 8192) ? 8192 : (int)avail;
        }
        vq_init<<<1, 512, 0, stream>>>(cb, c2, acc, cnt);
        vq_main_f32<<<M_TOKENS / BM, 256, 0, stream>>>(
            z, cb, c2, out, acc, cnt, list, cap);
        vq_refine<<<192, 256, 0, stream>>>(z, cb, c2, acc, cnt, list, out, cap);
    }
}

// Round 13
// 177.712 us; speedup vs baseline: 2.9410x; 2.9410x over previous
//
#include <hip/hip_runtime.h>

// Problem constants
#define M_TOKENS 65536      // 8 * 8192
#define HID      256
#define KCODES   512

#define IND_OFF  (M_TOKENS * HID)          // 16777216
#define LOSS_OFF (IND_OFF + M_TOKENS)      // 16842752

// Flag threshold: any token whose top-2 score gap is below this gets exact
// re-scoring with the emulated reference-f32 quantization pipeline.
// bf16-split GEMM worst-case score error ~5e-6 << TAU; grid 2*3.05e-5 < TAU.
#define TAU      1.5e-4f

// ws layout (fast path):
//   [0:8) double loss | [8:12) int cnt | [16:2064) c2[512]
//   [4096 : +256K) B_hi fragments | [266240 : +256K) B_lo | [528384 : +32K) list
#define WS_C2_OFF        16
#define WS_BHI_OFF       4096
#define WS_BLO_OFF       (4096 + 262144)
#define WS_LIST_OFF_FAST (4096 + 524288)
#define WS_LIST_OFF_SLOW 4096
#define WS_MIN_FAST      (WS_LIST_OFF_FAST + 8192 * 4)

typedef __attribute__((ext_vector_type(8))) short  short8;   // 8 bf16
typedef __attribute__((ext_vector_type(4))) float  f32x4;

__device__ inline unsigned short f2bf(float f) {             // RNE f32->bf16
    unsigned u = __float_as_uint(f);
    u += 0x7FFF + ((u >> 16) & 1);
    return (unsigned short)(u >> 16);
}
__device__ inline float bf2f(unsigned short h) {
    return __uint_as_float(((unsigned)h) << 16);
}

// ---------------------------------------------------------------------------
// prep: blocks 0..63 swizzle codebook into MFMA B-fragment order (bf16 hi/lo);
//       blocks 64..65 compute c2[k] (f64) and zero the accumulators.
// Fragment (nb, kb): lane l, elem j -> code = nb*16 + (l&15),
//                                      k = kb*32 + (l>>4)*8 + j.
// ---------------------------------------------------------------------------
__global__ __launch_bounds__(256) void vq_prep(
    const float* __restrict__ cb,
    unsigned short* __restrict__ Bhi, unsigned short* __restrict__ Blo,
    float* __restrict__ c2, double* __restrict__ acc, int* __restrict__ cnt) {
    int b = blockIdx.x;
    if (b < 64) {
        int g = b * 256 + threadIdx.x;   // 0..16383 = frag*64 + lane
        int frag = g >> 6, lane = g & 63;
        int nb = frag >> 3, kb = frag & 7;
        int code = nb * 16 + (lane & 15);
        int kk = kb * 32 + (lane >> 4) * 8;
        const float4* s4 = reinterpret_cast<const float4*>(cb + code * HID + kk);
        float4 v0 = s4[0], v1 = s4[1];
        float f[8] = {v0.x, v0.y, v0.z, v0.w, v1.x, v1.y, v1.z, v1.w};
        short8 vh, vl;
        #pragma unroll
        for (int j = 0; j < 8; ++j) {
            unsigned short h = f2bf(f[j]);
            vh[j] = (short)h;
            vl[j] = (short)f2bf(f[j] - bf2f(h));
        }
        *reinterpret_cast<short8*>(Bhi + (size_t)g * 8) = vh;
        *reinterpret_cast<short8*>(Blo + (size_t)g * 8) = vl;
    } else {
        if (b == 64 && threadIdx.x == 0) { *acc = 0.0; *cnt = 0; }
        int k = (b - 64) * 256 + threadIdx.x;   // 0..511
        const float* row = cb + k * HID;
        double s = 0.0;
        for (int i = 0; i < HID; ++i) {
            double v = (double)row[i];
            s = fma(v, v, s);
        }
        c2[k] = (float)s;
    }
}

// ---------------------------------------------------------------------------
// main MFMA kernel (round-10 geometry, measured best: 110us):
// 256 threads = 4 waves; wave owns 32 tokens (2 M-frags). Grid = 512 blocks
// (2 blocks/CU). BK=32 codes per phase (16 phases): per phase each wave
// stages 8 frags (global_load_lds w16) into double-buffered 32KB LDS, then
// runs 2 independent 16-code sub-chunks (96 MFMAs, 4 acc chains).
// setprio(1) around MFMA clusters. Top-2 only (top-3 spilled -- round 12).
// Loss algebraic (no z re-read).
// ---------------------------------------------------------------------------
__global__ __launch_bounds__(256, 2) void vq_main_mfma(
    const float* __restrict__ z, const float* __restrict__ cb,
    const float* __restrict__ c2g,
    const unsigned short* __restrict__ Bhi,
    const unsigned short* __restrict__ Blo,
    float* __restrict__ out, double* __restrict__ loss_acc,
    int* __restrict__ cnt, int* __restrict__ list, int cap) {

    __shared__ short8 ldsB[2][32][64];   // 2 bufs x 32KB = 64 KB
    __shared__ float  lds_c2[KCODES];    // 2 KB

    const int tid  = threadIdx.x;
    const int wid  = tid >> 6;
    const int lane = tid & 63;
    const int q    = lane >> 4;
    const int tokW = blockIdx.x * 128 + wid * 32;   // wave's first token

    const float4* z4  = reinterpret_cast<const float4*>(z);
    const float4* cb4 = reinterpret_cast<const float4*>(cb);

    // stage c2 into LDS
    lds_c2[tid]       = c2g[tid];
    lds_c2[tid + 256] = c2g[tid + 256];

    // stage one 32-code phase (32 frag-slots of 1KB): wave wid stages slots
    // wid*8 .. wid*8+7.  Slot s: g=s>>4 (16-code group), t=s&15 (0..7 hi,
    // 8..15 lo), kb=t&7.  Source frag index nb = 2*phase+g.
#define STAGE(kv, bufv) do {                                                   \
        _Pragma("unroll")                                                      \
        for (int j = 0; j < 8; ++j) {                                          \
            int s_  = (wid << 3) | j;                                          \
            int g_  = s_ >> 4;                                                 \
            int t_  = s_ & 15;                                                 \
            int kb_ = t_ & 7;                                                  \
            const unsigned short* src_ =                                       \
                ((t_ < 8) ? Bhi : Blo) +                                       \
                (((size_t)((2 * (kv) + g_) * 8 + kb_) * 64 + lane) << 3);      \
            __builtin_amdgcn_global_load_lds(                                  \
                (const __attribute__((address_space(1))) void*)src_,           \
                (__attribute__((address_space(3))) void*)&ldsB[bufv][s_][0],   \
                16, 0, 0);                                                     \
        }                                                                      \
    } while (0)

    // issue phase-0 stage FIRST so it streams in under the A-load/convert
    STAGE(0, 0);

    // ---- load wave's 32 z rows as A fragments (bf16 hi/lo) + z2 ----
    // A frag (mf,kb): lane holds token tokW+mf*16+(l&15), k = kb*32+(l>>4)*8+j
    short8 ah[2][8], al[2][8];
    float sq[2];
    #pragma unroll
    for (int mf = 0; mf < 2; ++mf) {
        int token = tokW + mf * 16 + (lane & 15);
        const float4* zr = z4 + (size_t)token * 64 + q * 2;
        float s = 0.f;
        #pragma unroll
        for (int kb = 0; kb < 8; ++kb) {
            float4 v0 = zr[kb * 8];
            float4 v1 = zr[kb * 8 + 1];
            float f[8] = {v0.x, v0.y, v0.z, v0.w, v1.x, v1.y, v1.z, v1.w};
            short8 vh, vl;
            #pragma unroll
            for (int j = 0; j < 8; ++j) {
                unsigned short h = f2bf(f[j]);
                vh[j] = (short)h;
                vl[j] = (short)f2bf(f[j] - bf2f(h));
                s = fmaf(f[j], f[j], s);
            }
            ah[mf][kb] = vh;
            al[mf][kb] = vl;
        }
        // z2 of token tokW+mf*16+(lane&15), replicated across q-groups
        s += __shfl_xor(s, 16, 64);
        s += __shfl_xor(s, 32, 64);
        sq[mf] = s;
    }

    // per-lane running top-2 for 2 mfrags x 4 rows
    float b1[2][4], b2[2][4];
    int   i1[2][4];
    #pragma unroll
    for (int mf = 0; mf < 2; ++mf)
        #pragma unroll
        for (int r = 0; r < 4; ++r) { b1[mf][r] = 3.4e38f; b2[mf][r] = 3.4e38f; i1[mf][r] = 0; }

    // ---- main loop over 16 phases of 32 codes; dbuf, 1 barrier/phase ----
    #pragma unroll 2
    for (int k = 0; k < 16; ++k) {
        int buf = k & 1;
        __syncthreads();                    // phase-k data landed; buf^1 free
        if (k < 15) STAGE(k + 1, buf ^ 1);  // async prefetch under compute

        #pragma unroll
        for (int g = 0; g < 2; ++g) {
            f32x4 a0 = {0.f, 0.f, 0.f, 0.f};
            f32x4 a1 = {0.f, 0.f, 0.f, 0.f};
            __builtin_amdgcn_s_setprio(1);
            #pragma unroll
            for (int kb = 0; kb < 8; ++kb) {
                short8 vbh = ldsB[buf][g * 16 + kb][lane];
                short8 vbl = ldsB[buf][g * 16 + 8 + kb][lane];
                a0 = __builtin_amdgcn_mfma_f32_16x16x32_bf16(ah[0][kb], vbh, a0, 0, 0, 0);
                a1 = __builtin_amdgcn_mfma_f32_16x16x32_bf16(ah[1][kb], vbh, a1, 0, 0, 0);
                a0 = __builtin_amdgcn_mfma_f32_16x16x32_bf16(al[0][kb], vbh, a0, 0, 0, 0);
                a1 = __builtin_amdgcn_mfma_f32_16x16x32_bf16(al[1][kb], vbh, a1, 0, 0, 0);
                a0 = __builtin_amdgcn_mfma_f32_16x16x32_bf16(ah[0][kb], vbl, a0, 0, 0, 0);
                a1 = __builtin_amdgcn_mfma_f32_16x16x32_bf16(ah[1][kb], vbl, a1, 0, 0, 0);
            }
            __builtin_amdgcn_s_setprio(0);
            int code = (2 * k + g) * 16 + (lane & 15);
            float c2v = lds_c2[code];
            #pragma unroll
            for (int r = 0; r < 4; ++r) {
                float s0 = fmaf(-2.f, a0[r], c2v);   // c2 - 2*cross
                if (s0 < b1[0][r]) { b2[0][r] = b1[0][r]; b1[0][r] = s0; i1[0][r] = code; }
                else if (s0 < b2[0][r]) b2[0][r] = s0;
                float s1 = fmaf(-2.f, a1[r], c2v);
                if (s1 < b1[1][r]) { b2[1][r] = b1[1][r]; b1[1][r] = s1; i1[1][r] = code; }
                else if (s1 < b2[1][r]) b2[1][r] = s1;
            }
        }
    }
#undef STAGE

    // ---- merge top-2 across the 16 lanes of each row group ----
    #pragma unroll
    for (int st = 1; st <= 8; st <<= 1) {
        #pragma unroll
        for (int mf = 0; mf < 2; ++mf)
            #pragma unroll
            for (int r = 0; r < 4; ++r) {
                float ob1 = __shfl_xor(b1[mf][r], st, 64);
                int   oi1 = __shfl_xor(i1[mf][r], st, 64);
                float ob2 = __shfl_xor(b2[mf][r], st, 64);
                if (ob1 < b1[mf][r] || (ob1 == b1[mf][r] && oi1 < i1[mf][r])) {
                    b2[mf][r] = fminf(b1[mf][r], ob2);
                    b1[mf][r] = ob1;
                    i1[mf][r] = oi1;
                } else {
                    b2[mf][r] = fminf(b2[mf][r], ob1);
                }
            }
    }

    // ---- indices + ambiguity flags ----
    if ((lane & 15) == 0) {
        #pragma unroll
        for (int mf = 0; mf < 2; ++mf) {
            float4 iv;
            #pragma unroll
            for (int r = 0; r < 4; ++r) {
                ((float*)&iv)[r] = (float)i1[mf][r];
                if (b2[mf][r] - b1[mf][r] <= TAU) {
                    int pos = atomicAdd(cnt, 1);
                    if (pos < cap) list[pos] = tokW + mf * 16 + q * 4 + r;
                }
            }
            *reinterpret_cast<float4*>(out + IND_OFF + tokW + mf * 16 + q * 4) = iv;
        }
    }

    // ---- loss: ||zq-z||^2 = z2 + (c2_best - 2 cross_best) = z2 + b1 ----
    double lsum = 0.0;
    #pragma unroll
    for (int mf = 0; mf < 2; ++mf)
        #pragma unroll
        for (int r = 0; r < 4; ++r) {
            float z2r = __shfl(sq[mf], (lane & 48) | (q * 4 + r), 64);
            if ((lane & 15) == 0) lsum += (double)z2r + (double)b1[mf][r];
        }
    lsum += __shfl_xor(lsum, 16, 64);
    lsum += __shfl_xor(lsum, 32, 64);
    if (lane == 0) atomicAdd(loss_acc, lsum);

    // ---- gather z_q rows from codebook, write out ----
    float4* out4 = reinterpret_cast<float4*>(out);
    #pragma unroll
    for (int tt = 0; tt < 32; ++tt) {
        int code = __shfl(i1[tt >> 4][tt & 3], ((tt >> 2) & 3) * 16, 64);
        float4 cv = cb4[(size_t)code * 64 + lane];
        out4[(size_t)(tokW + tt) * 64 + lane] = cv;
    }
}

// ---------------------------------------------------------------------------
// FALLBACK (small ws): round-3 f32 VALU kernel, verified correct.
// ---------------------------------------------------------------------------
#define BM   128
#define NC   128
#define KS   32
#define PAD  33

__global__ void vq_init(const float* __restrict__ cb, float* __restrict__ c2,
                        double* __restrict__ acc, int* __restrict__ cnt) {
    int k = threadIdx.x;
    if (k == 0) { *acc = 0.0; *cnt = 0; }
    const float* row = cb + k * HID;
    double s = 0.0;
    for (int i = 0; i < HID; ++i) {
        double v = (double)row[i];
        s = fma(v, v, s);
    }
    c2[k] = (float)s;
}

__global__ __launch_bounds__(256, 2) void vq_main_f32(
    const float* __restrict__ z, const float* __restrict__ cb,
    const float* __restrict__ c2g, float* __restrict__ out,
    double* __restrict__ loss_acc, int* __restrict__ cnt,
    int* __restrict__ list, int cap) {

    __shared__ float smem[(BM + NC) * PAD];
    float* zs = smem;
    float* cs = smem + BM * PAD;

    const int tid = threadIdx.x;
    const int tx = tid & 15;
    const int ty = tid >> 4;
    const int tokBase = blockIdx.x * BM;

    const float4* z4g  = reinterpret_cast<const float4*>(z);
    const float4* cb4g = reinterpret_cast<const float4*>(cb);

    float bs[8], bs2[8];
    int   bi[8];
    #pragma unroll
    for (int m = 0; m < 8; ++m) { bs[m] = 3.4e38f; bs2[m] = 3.4e38f; bi[m] = 0; }

    for (int chunk = 0; chunk < KCODES / NC; ++chunk) {
        float acc[8][8];
        #pragma unroll
        for (int m = 0; m < 8; ++m)
            #pragma unroll
            for (int n = 0; n < 8; ++n) acc[m][n] = 0.f;

        for (int ks = 0; ks < HID / KS; ++ks) {
            __syncthreads();
            #pragma unroll
            for (int i = 0; i < 4; ++i) {
                int f   = tid + i * 256;
                int row = f >> 3;
                int k4  = f & 7;
                float4 zv = z4g[(tokBase + row) * (HID / 4) + ks * (KS / 4) + k4];
                int b = row * PAD + k4 * 4;
                zs[b + 0] = zv.x; zs[b + 1] = zv.y; zs[b + 2] = zv.z; zs[b + 3] = zv.w;
                float4 cv = cb4g[(chunk * NC + row) * (HID / 4) + ks * (KS / 4) + k4];
                cs[b + 0] = cv.x; cs[b + 1] = cv.y; cs[b + 2] = cv.z; cs[b + 3] = cv.w;
            }
            __syncthreads();

            #pragma unroll 2
            for (int k = 0; k < KS; ++k) {
                float zf[8], cf[8];
                #pragma unroll
                for (int m = 0; m < 8; ++m) zf[m] = zs[(ty * 8 + m) * PAD + k];
                #pragma unroll
                for (int n = 0; n < 8; ++n) cf[n] = cs[(tx * 8 + n) * PAD + k];
                #pragma unroll
                for (int m = 0; m < 8; ++m)
                    #pragma unroll
                    for (int n = 0; n < 8; ++n)
                        acc[m][n] = fmaf(zf[m], cf[n], acc[m][n]);
            }
        }

        #pragma unroll
        for (int n = 0; n < 8; ++n) {
            int code = chunk * NC + tx * 8 + n;
            float c2v = c2g[code];
            #pragma unroll
            for (int m = 0; m < 8; ++m) {
                float s = fmaf(-2.f, acc[m][n], c2v);
                if (s < bs[m]) { bs2[m] = bs[m]; bs[m] = s; bi[m] = code; }
                else if (s < bs2[m]) bs2[m] = s;
            }
        }
    }

    __syncthreads();
    float* rs   = smem;
    int*   ri   = reinterpret_cast<int*>(smem + BM * 16);
    float* rs2  = smem + BM * 32;
    int*   inds = reinterpret_cast<int*>(smem + BM * 48);
    float* wred = smem + BM * 48 + BM;

    #pragma unroll
    for (int m = 0; m < 8; ++m) {
        int tok = ty * 8 + m;
        rs [tok * 16 + tx] = bs[m];
        ri [tok * 16 + tx] = bi[m];
        rs2[tok * 16 + tx] = bs2[m];
    }
    __syncthreads();

    if (tid < BM) {
        float B1 = rs[tid * 16];
        int   I1 = ri[tid * 16];
        float B2 = rs2[tid * 16];
        for (int j = 1; j < 16; ++j) {
            float b1v = rs [tid * 16 + j];
            int   i1v = ri [tid * 16 + j];
            float b2v = rs2[tid * 16 + j];
            if (b1v < B1 || (b1v == B1 && i1v < I1)) {
                B2 = fminf(B1, b2v); B1 = b1v; I1 = i1v;
            } else {
                B2 = fminf(B2, b1v);
            }
        }
        inds[tid] = I1;
        out[IND_OFF + tokBase + tid] = (float)I1;
        if (B2 - B1 <= TAU) {
            int pos = atomicAdd(cnt, 1);
            if (pos < cap) list[pos] = tokBase + tid;
        }
    }
    __syncthreads();

    float loc = 0.f;
    float4* out4 = reinterpret_cast<float4*>(out);
    for (int it = 0; it < (BM * HID / 4) / 256; ++it) {
        int e4  = it * 256 + tid;
        int tok = e4 >> 6;
        int h4  = e4 & 63;
        int code = inds[tok];
        float4 cv = cb4g[code * 64 + h4];
        float4 zv = z4g[(tokBase + tok) * 64 + h4];
        out4[(tokBase + tok) * 64 + h4] = cv;
        float dx = cv.x - zv.x, dy = cv.y - zv.y;
        float dz = cv.z - zv.z, dw = cv.w - zv.w;
        loc = fmaf(dx, dx, loc);
        loc = fmaf(dy, dy, loc);
        loc = fmaf(dz, dz, loc);
        loc = fmaf(dw, dw, loc);
    }
    #pragma unroll
    for (int off = 32; off > 0; off >>= 1) loc += __shfl_xor(loc, off, 64);
    int wave = tid >> 6;
    if ((tid & 63) == 0) wred[wave] = loc;
    __syncthreads();
    if (tid == 0) {
        double t = (double)wred[0] + (double)wred[1] +
                   (double)wred[2] + (double)wred[3];
        atomicAdd(loss_acc, t);
    }
}

// ---------------------------------------------------------------------------
// refine: BATCHED (8 tokens/block share one codebook pass) re-score of
// flagged tokens with the EMULATED reference f32 pipeline:
//   D_k = fl32( fl32(z2 - fl32(2*cross_k)) + c2_k ),  argmin first-index.
// Also finalizes the loss output (block 0, thread 0).
// ---------------------------------------------------------------------------
#define RT 8
__global__ __launch_bounds__(256) void vq_refine(
    const float* __restrict__ z, const float* __restrict__ cb,
    const float* __restrict__ c2g, const double* __restrict__ loss_acc,
    const int* __restrict__ cnt, const int* __restrict__ list,
    float* __restrict__ out, int cap) {

    if (blockIdx.x == 0 && threadIdx.x == 0)
        out[LOSS_OFF] = (float)(2.0 * (*loss_acc) / (double)(M_TOKENS * HID));

    __shared__ float  zrow[RT][HID];
    __shared__ double redd[RT][256];
    __shared__ int    redi[RT][256];

    const int tid = threadIdx.x;
    int n = *cnt; if (n > cap) n = cap;

    for (int base = blockIdx.x * RT; base < n; base += gridDim.x * RT) {
        int toks[RT];
        #pragma unroll
        for (int t = 0; t < RT; ++t) {
            int ii = base + t;
            if (ii > n - 1) ii = n - 1;   // pad with last (idempotent dup)
            toks[t] = list[ii];
        }
        #pragma unroll
        for (int t = 0; t < RT; ++t) {
            float v = z[(size_t)toks[t] * HID + tid];
            zrow[t][tid] = v;
            redd[t][tid] = (double)v * (double)v;
        }
        __syncthreads();
        for (int s = 128; s > 0; s >>= 1) {
            if (tid < s) {
                #pragma unroll
                for (int t = 0; t < RT; ++t) redd[t][tid] += redd[t][tid + s];
            }
            __syncthreads();
        }
        float z2f[RT];
        #pragma unroll
        for (int t = 0; t < RT; ++t) z2f[t] = (float)redd[t][0];
        __syncthreads();

        double bd[RT];
        int    bk[RT];
        #pragma unroll
        for (int t = 0; t < RT; ++t) { bd[t] = 1e300; bk[t] = 1 << 30; }

        for (int c = 0; c < 2; ++c) {
            int k = tid + c * 256;
            const float4* cr = reinterpret_cast<const float4*>(cb + (size_t)k * HID);
            double acc[RT];
            #pragma unroll
            for (int t = 0; t < RT; ++t) acc[t] = 0.0;
            for (int i = 0; i < HID / 4; ++i) {
                float4 cv = cr[i];
                #pragma unroll
                for (int t = 0; t < RT; ++t) {
                    float4 zv = *reinterpret_cast<const float4*>(&zrow[t][i * 4]);
                    acc[t] = fma((double)zv.x, (double)cv.x, acc[t]);
                    acc[t] = fma((double)zv.y, (double)cv.y, acc[t]);
                    acc[t] = fma((double)zv.z, (double)cv.z, acc[t]);
                    acc[t] = fma((double)zv.w, (double)cv.w, acc[t]);
                }
            }
            float c2v = c2g[k];
            #pragma unroll
            for (int t = 0; t < RT; ++t) {
                float cross32 = (float)acc[t];                 // fl32(cross)
                float u = 2.0f * cross32;                      // exact
                float tq = (float)((double)z2f[t] - (double)u);// fl32(z2-u)
                float D = (float)((double)tq + (double)c2v);   // fl32(t+c2)
                double Dd = (double)D;
                if (Dd < bd[t] || (Dd == bd[t] && k < bk[t])) { bd[t] = Dd; bk[t] = k; }
            }
        }
        #pragma unroll
        for (int t = 0; t < RT; ++t) { redd[t][tid] = bd[t]; redi[t][tid] = bk[t]; }
        __syncthreads();
        for (int s = 128; s > 0; s >>= 1) {
            if (tid < s) {
                #pragma unroll
                for (int t = 0; t < RT; ++t) {
                    double d2 = redd[t][tid + s]; int i2v = redi[t][tid + s];
                    if (d2 < redd[t][tid] ||
                        (d2 == redd[t][tid] && i2v < redi[t][tid])) {
                        redd[t][tid] = d2; redi[t][tid] = i2v;
                    }
                }
            }
            __syncthreads();
        }
        if (tid < RT) out[IND_OFF + toks[tid]] = (float)redi[tid][0];
        #pragma unroll
        for (int t = 0; t < RT; ++t) {
            int best = redi[t][0];
            out[(size_t)toks[t] * HID + tid] = cb[(size_t)best * HID + tid];
        }
        __syncthreads();
    }
}

extern "C" void kernel_launch(void* const* d_in, const int* in_sizes, int n_in,
                              void* d_out, int out_size, void* d_ws, size_t ws_size,
                              hipStream_t stream) {
    const float* z  = (const float*)d_in[0];
    const float* cb = (const float*)d_in[1];
    float* out = (float*)d_out;
    double* acc = (double*)d_ws;
    int*  cnt = (int*)((char*)d_ws + 8);
    float* c2 = (float*)((char*)d_ws + WS_C2_OFF);

    if (ws_size >= WS_MIN_FAST) {
        unsigned short* Bhi = (unsigned short*)((char*)d_ws + WS_BHI_OFF);
        unsigned short* Blo = (unsigned short*)((char*)d_ws + WS_BLO_OFF);
        int* list = (int*)((char*)d_ws + WS_LIST_OFF_FAST);
        int cap = 8192;
        vq_prep<<<66, 256, 0, stream>>>(cb, Bhi, Blo, c2, acc, cnt);
        vq_main_mfma<<<M_TOKENS / 128, 256, 0, stream>>>(
            z, cb, c2, Bhi, Blo, out, acc, cnt, list, cap);
        vq_refine<<<128, 256, 0, stream>>>(z, cb, c2, acc, cnt, list, out, cap);
    } else {
        int* list = (int*)((char*)d_ws + WS_LIST_OFF_SLOW);
        int cap = 0;
        if (ws_size > WS_LIST_OFF_SLOW + 16) {
            size_t avail = (ws_size - WS_LIST_OFF_SLOW) / 4;
            cap = (avail > 8192) ? 8192 : (int)avail;
        }
        vq_init<<<1, 512, 0, stream>>>(cb, c2, acc, cnt);
        vq_main_f32<<<M_TOKENS / BM, 256, 0, stream>>>(
            z, cb, c2, out, acc, cnt, list, cap);
        vq_refine<<<128, 256, 0, stream>>>(z, cb, c2, acc, cnt, list, out, cap);
    }
}